// Round 18
// baseline (222.148 us; speedup 1.0000x reference)
//
#include <hip/hip_runtime.h>
#include <hip/hip_bf16.h>
#include <math.h>

#define B_ 4
#define T_ 4096
#define D_ 2048
#define E_ 8
#define C_ 1024
#define H_ 256
#define SLOTCAP 32

typedef unsigned short u16;
typedef unsigned long long u64;
typedef __attribute__((ext_vector_type(8))) short short8;
typedef __attribute__((ext_vector_type(4))) float f32x4;

__device__ __forceinline__ u16 f2bf_n(float f) {
    union { __hip_bfloat16 b; u16 u; } v;
    v.b = __float2bfloat16(f);
    return v.u;
}
__device__ __forceinline__ float bf2f(u16 u) {
    union { unsigned u; float f; } v; v.u = ((unsigned)u) << 16;
    return v.f;
}

// swizzled u16 index into a [rows][64] tile: 8-u16 chunk XOR'd by row&7
__device__ __forceinline__ int swz(int row, int chunk) {
    return (row << 6) + ((chunk ^ (row & 7)) << 3);
}

// async global->LDS, 16B per lane; dst wave-uniform base (HW adds lane*16)
__device__ __forceinline__ void gload16(const void* g, void* l) {
    __builtin_amdgcn_global_load_lds(
        (const __attribute__((address_space(1))) void*)g,
        (__attribute__((address_space(3))) void*)l, 16, 0, 0);
}

// ---------------- plain f32 -> bf16 (row-major W1) ----------------
__global__ __launch_bounds__(256) void conv_f32_bf16(
    const float* __restrict__ src, u16* __restrict__ dst, int n)
{
    int i = (blockIdx.x * 256 + threadIdx.x) * 4;
    if (i >= n) return;
    f32x4 v = *reinterpret_cast<const f32x4*>(src + i);
    u16 o[4];
    o[0] = f2bf_n(v[0]); o[1] = f2bf_n(v[1]); o[2] = f2bf_n(v[2]); o[3] = f2bf_n(v[3]);
    *reinterpret_cast<u64*>(dst + i) = *reinterpret_cast<const u64*>(o);
}

// ---------------- W2 -> swizzled tile image ----------------
// image[e][nt(8)][kt(4)][row(256)][sc(8)]
__global__ __launch_bounds__(256) void conv_w2_img(
    const float* __restrict__ W2, u16* __restrict__ img)
{
    const int cid = blockIdx.x * 256 + threadIdx.x;
    const int e = cid >> 16;
    const int nt = (cid >> 13) & 7;
    const int kt = (cid >> 11) & 3;
    const int row = (cid >> 3) & 255;
    const int sc = cid & 7;
    const float* s = W2 + (((size_t)e * 2048 + nt * 256 + row) * 256 + kt * 64
                           + ((sc ^ (row & 7)) << 3));
    f32x4 v0 = *reinterpret_cast<const f32x4*>(s);
    f32x4 v1 = *reinterpret_cast<const f32x4*>(s + 4);
    u16 o[8];
    #pragma unroll
    for (int j = 0; j < 4; ++j) { o[j] = f2bf_n(v0[j]); o[j + 4] = f2bf_n(v1[j]); }
    *reinterpret_cast<short8*>(img + (size_t)cid * 8) =
        *reinterpret_cast<const short8*>(o);
}

// ---------------- zero cnt ----------------
__global__ __launch_bounds__(256) void zero_cnt(int* __restrict__ cnt)
{
    const int i = (blockIdx.x * 256 + threadIdx.x) * 4;
    *reinterpret_cast<f32x4*>(cnt + i) = (f32x4){0.f, 0.f, 0.f, 0.f};
}

// ---------------- GEMM1 v13: v12 structure at exactly 80 KB -> 2 blocks/CU --
// 128x256 tile, 8 waves 2Mx4N; As SINGLE 16 KB, Bs dbuf 64 KB; no aux LDS.
// Per iter: B_WRITE(alt) overlaps MFMA; A single-buffered via 2nd barrier.
// Global loads never drained mid-loop. grid (x=32 be -> XCD=e, y=8 mt2).
__global__ __launch_bounds__(512) void gemm1_v13(
    const float* __restrict__ x, const u16* __restrict__ W1bf,
    const float* __restrict__ b1, const int* __restrict__ idx,
    u16* __restrict__ Himg)
{
    const int be = blockIdx.x;          // XCD = be%8 = e
    const int mt2 = blockIdx.y;         // 0..7
    const int b = be >> 3, e = be & 7;
    const int m0 = mt2 * 128;

    __shared__ __align__(16) u16 As[128 * 64];      // 16 KB (single)
    __shared__ __align__(16) u16 Bs[2][256 * 64];   // 2 x 32 KB

    const int tid = threadIdx.x;
    const int lane = tid & 63, wid = tid >> 6;
    const int wm = wid >> 2, wn = wid & 3;
    const int l15 = lane & 15, lk = lane >> 4;

    // A staging: row ar (0..127), chunks ac0 / ac0+4 (f32 source, cvt here)
    const int ar = tid >> 2, ac0 = tid & 3;
    const int tok = idx[(b * E_ + e) * C_ + m0 + ar];   // L2-cached broadcast
    const float* aRow = x + (size_t)b * (T_ * (size_t)D_) + (size_t)tok * D_;
    // B staging: row br (0..255), chunks bc0..bc0+3 (bf16 source)
    const int br = tid >> 1, bc0 = (tid & 1) * 4;
    const u16* bRow = W1bf + ((size_t)e * H_ + br) * D_;

    const int aOff0 = swz(ar, ac0), aOff1 = swz(ar, ac0 + 4);
    int bOff[4];
    #pragma unroll
    for (int j = 0; j < 4; ++j) bOff[j] = swz(br, bc0 + j);

    f32x4 acc[4][4];
    #pragma unroll
    for (int i = 0; i < 4; ++i)
        #pragma unroll
        for (int j = 0; j < 4; ++j)
            acc[i][j] = (f32x4){0.f, 0.f, 0.f, 0.f};

    f32x4 pa[4];
    short8 pb[4];

#define G1_LOAD(k)                                                            \
    do {                                                                      \
        pa[0] = *reinterpret_cast<const f32x4*>(aRow + (k) + ac0 * 8);        \
        pa[1] = *reinterpret_cast<const f32x4*>(aRow + (k) + ac0 * 8 + 4);    \
        pa[2] = *reinterpret_cast<const f32x4*>(aRow + (k) + (ac0 + 4) * 8);  \
        pa[3] = *reinterpret_cast<const f32x4*>(aRow + (k) + (ac0 + 4) * 8 + 4);\
        _Pragma("unroll")                                                     \
        for (int j = 0; j < 4; ++j)                                           \
            pb[j] = *reinterpret_cast<const short8*>(bRow + (k) + (bc0 + j) * 8);\
    } while (0)

#define A_WRITE()                                                             \
    do {                                                                      \
        short8 s0, s1;                                                        \
        _Pragma("unroll")                                                     \
        for (int r = 0; r < 4; ++r) {                                         \
            s0[r] = (short)f2bf_n(pa[0][r]); s0[r + 4] = (short)f2bf_n(pa[1][r]); \
            s1[r] = (short)f2bf_n(pa[2][r]); s1[r + 4] = (short)f2bf_n(pa[3][r]); \
        }                                                                     \
        *reinterpret_cast<short8*>(&As[aOff0]) = s0;                          \
        *reinterpret_cast<short8*>(&As[aOff1]) = s1;                          \
    } while (0)

#define B_WRITE(buf)                                                          \
    do {                                                                      \
        _Pragma("unroll")                                                     \
        for (int j = 0; j < 4; ++j)                                           \
            *reinterpret_cast<short8*>(&Bs[buf][bOff[j]]) = pb[j];            \
    } while (0)

    // prologue: tile 0 into As + Bs[0]; tile 1 into regs
    G1_LOAD(0);
    A_WRITE();
    B_WRITE(0);
    G1_LOAD(64);
    asm volatile("s_waitcnt lgkmcnt(0)" ::: "memory");
    __builtin_amdgcn_s_barrier();

    const int NT = D_ / 64;  // 32
    for (int t = 0; t < NT; ++t) {
        const int cur = t & 1;
        if (t + 1 < NT) B_WRITE(cur ^ 1);   // dbuf side: overlaps MFMA below
        #pragma unroll
        for (int kk = 0; kk < 2; ++kk) {
            short8 af[4], bfr[4];
            #pragma unroll
            for (int m = 0; m < 4; ++m) {
                const int row = wm * 64 + m * 16 + l15;
                af[m] = *reinterpret_cast<const short8*>(
                    &As[swz(row, kk * 4 + lk)]);
            }
            #pragma unroll
            for (int n = 0; n < 4; ++n) {
                const int row = wn * 64 + n * 16 + l15;
                bfr[n] = *reinterpret_cast<const short8*>(
                    &Bs[cur][swz(row, kk * 4 + lk)]);
            }
            __builtin_amdgcn_s_setprio(1);
            #pragma unroll
            for (int m = 0; m < 4; ++m)
                #pragma unroll
                for (int n = 0; n < 4; ++n)
                    acc[m][n] = __builtin_amdgcn_mfma_f32_16x16x32_bf16(
                        bfr[n], af[m], acc[m][n], 0, 0, 0);
            __builtin_amdgcn_s_setprio(0);
        }
        // all waves' reads of As (t) and Bs[cur] done; B(t+1) writes drained too
        asm volatile("s_waitcnt lgkmcnt(0)" ::: "memory");
        __builtin_amdgcn_s_barrier();
        if (t + 1 < NT) {
            A_WRITE();                       // single-buffer A: write t+1 now
            if (t + 2 < NT) G1_LOAD((t + 2) * 64);  // after A_WRITE used pa
            asm volatile("s_waitcnt lgkmcnt(0)" ::: "memory");
            __builtin_amdgcn_s_barrier();    // A(t+1) visible to all
        }
    }
#undef G1_LOAD
#undef A_WRITE
#undef B_WRITE

    // epilogue: bias + exact gelu -> Himg (64-row tile images, gemm2 A layout)
    #pragma unroll
    for (int m = 0; m < 4; ++m) {
        const int cl = wm * 64 + m * 16 + l15;
        const int row = cl & 63;
        const size_t hblk =
            ((size_t)(be * 16 + mt2 * 2 + (cl >> 6)) * 4 + wn) * 4096;
        #pragma unroll
        for (int n = 0; n < 4; ++n) {
            const int hb = wn * 64 + n * 16 + lk * 4;
            f32x4 bias = *reinterpret_cast<const f32x4*>(&b1[e * H_ + hb]);
            u16 o[4];
            #pragma unroll
            for (int r = 0; r < 4; ++r) {
                float h = acc[m][n][r] + bias[r];
                float g = 0.5f * h * (1.0f + erff(h * 0.70710678118f));
                o[r] = f2bf_n(g);
            }
            const int lc = (n * 2 + (lk >> 1)) ^ (row & 7);
            u16* p = Himg + hblk + row * 64 + lc * 8 + (lk & 1) * 4;
            *reinterpret_cast<u64*>(p) = *reinterpret_cast<const u64*>(o);
        }
    }
}

// ---------------- GEMM2 v8: persistent B-panel; no store drain in loop -----
__global__ __launch_bounds__(512) void gemm2_v8(
    const u16* __restrict__ Himg, const u16* __restrict__ W2img,
    const float* __restrict__ b2, const float* __restrict__ gate,
    u16* __restrict__ Ybuf)
{
    const int be = blockIdx.x;          // XCD = be%8 = e
    const int nt = blockIdx.y;          // 0..7
    const int b = be >> 3, e = be & 7;
    const int n0 = nt * 256;

    __shared__ __align__(16) u16 As[16384];   // 32 KB: [kt4][row64][sc8]
    __shared__ __align__(16) u16 Bs[65536];   // 128 KB: [kt4][row256][sc8]

    const int tid = threadIdx.x;
    const int lane = tid & 63, wid = tid >> 6;
    const int wm = wid >> 2, wn = wid & 3;
    const int l15 = lane & 15, lk = lane >> 4;
    const int wofs = wid * 512;

    const u16* bPanel = W2img + (size_t)(e * 8 + nt) * 65536;
    #pragma unroll
    for (int j = 0; j < 16; ++j)
        gload16(bPanel + (size_t)(j * 512 + tid) * 8, &Bs[j * 4096 + wofs]);

    const u16* aBase = Himg + (size_t)(be * 16) * 16384 + (size_t)tid * 8;

#define A_ISSUE(mt)                                                           \
    do {                                                                      \
        const u16* a_ = aBase + (size_t)(mt) * 16384;                         \
        gload16(a_,          &As[wofs]);                                      \
        gload16(a_ + 4096,   &As[4096 + wofs]);                               \
        gload16(a_ + 8192,   &As[8192 + wofs]);                               \
        gload16(a_ + 12288,  &As[12288 + wofs]);                              \
    } while (0)

    A_ISSUE(0);

    f32x4 bias[4];
    #pragma unroll
    for (int n = 0; n < 4; ++n)
        bias[n] = *reinterpret_cast<const f32x4*>(
            &b2[n0 + wn * 64 + n * 16 + lk * 4]);

    const int gbase = (b * E_ + e) * C_ + wm * 32 + l15;
    const size_t ybase = (size_t)(b * E_ + e) * C_;

    float gc0 = gate[gbase];
    float gc1 = gate[gbase + 16];

    asm volatile("s_waitcnt vmcnt(0)" ::: "memory");   // B panel + A(0) + gate
    __builtin_amdgcn_s_barrier();
    __builtin_amdgcn_sched_barrier(0);

    for (int mt = 0; mt < 16; ++mt) {
        f32x4 acc[2][4];
        #pragma unroll
        for (int i = 0; i < 2; ++i)
            #pragma unroll
            for (int j = 0; j < 4; ++j)
                acc[i][j] = (f32x4){0.f, 0.f, 0.f, 0.f};

        #pragma unroll
        for (int t = 0; t < 4; ++t) {
            #pragma unroll
            for (int kk = 0; kk < 2; ++kk) {
                short8 af[2], bfr[4];
                #pragma unroll
                for (int m = 0; m < 2; ++m) {
                    const int row = wm * 32 + m * 16 + l15;
                    af[m] = *reinterpret_cast<const short8*>(
                        &As[t * 4096 + swz(row, kk * 4 + lk)]);
                }
                #pragma unroll
                for (int n = 0; n < 4; ++n) {
                    const int row = wn * 64 + n * 16 + l15;
                    bfr[n] = *reinterpret_cast<const short8*>(
                        &Bs[t * 16384 + swz(row, kk * 4 + lk)]);
                }
                __builtin_amdgcn_s_setprio(1);
                #pragma unroll
                for (int m = 0; m < 2; ++m)
                    #pragma unroll
                    for (int n = 0; n < 4; ++n)
                        acc[m][n] = __builtin_amdgcn_mfma_f32_16x16x32_bf16(
                            bfr[n], af[m], acc[m][n], 0, 0, 0);
                __builtin_amdgcn_s_setprio(0);
            }
        }

        asm volatile("s_waitcnt lgkmcnt(0)" ::: "memory");
        __builtin_amdgcn_s_barrier();
        __builtin_amdgcn_sched_barrier(0);

        if (mt < 15) A_ISSUE(mt + 1);
        float gn0 = 0.f, gn1 = 0.f;
        if (mt < 15) {
            gn0 = gate[gbase + (mt + 1) * 64];
            gn1 = gate[gbase + (mt + 1) * 64 + 16];
        }

        #pragma unroll
        for (int m = 0; m < 2; ++m) {
            const int cl = wm * 32 + m * 16 + l15;
            const float g = (m == 0) ? gc0 : gc1;
            u16* rowp = Ybuf + (ybase + mt * 64 + cl) * (size_t)D_ + n0;
            #pragma unroll
            for (int n = 0; n < 4; ++n) {
                const int db = wn * 64 + n * 16 + lk * 4;
                u16 o[4];
                #pragma unroll
                for (int r = 0; r < 4; ++r)
                    o[r] = f2bf_n((acc[m][n][r] + bias[n][r]) * g);
                *reinterpret_cast<u64*>(rowp + db) =
                    *reinterpret_cast<const u64*>(o);
            }
        }

        if (mt < 15) {
            // newest 18 = 16 stores + 2 gate loads -> A(mt+1) retired,
            // stores free-run
            asm volatile("s_waitcnt vmcnt(18)" ::: "memory");
            __builtin_amdgcn_s_barrier();
            __builtin_amdgcn_sched_barrier(0);
        }
        gc0 = gn0; gc1 = gn1;
    }
#undef A_ISSUE
}

// ---------------- inverted index build ----------------
__global__ __launch_bounds__(256) void fill_kernel(
    const int* __restrict__ idx, int* __restrict__ cnt,
    int* __restrict__ slots)
{
    int i = blockIdx.x * 256 + threadIdx.x;
    if (i >= B_ * E_ * C_) return;
    int b = i / (E_ * C_);
    int slot = i % (E_ * C_);
    int t = idx[i];
    int p = atomicAdd(&cnt[b * T_ + t], 1);
    if (p < SLOTCAP) slots[(b * T_ + t) * SLOTCAP + p] = slot;
}

// ---------------- combine: out[b,t,:] = sum over slots of Ybuf ----------------
__global__ __launch_bounds__(256) void combine_kernel(
    const u16* __restrict__ Ybuf, const int* __restrict__ cnt,
    const int* __restrict__ slots, float* __restrict__ out)
{
    const int bt = blockIdx.x;               // b*T_ + t
    const int tid = threadIdx.x;
    __shared__ int sl[SLOTCAP];
    int n = cnt[bt];
    n = n > SLOTCAP ? SLOTCAP : n;
    if (tid < n) sl[tid] = slots[bt * SLOTCAP + tid];
    __syncthreads();
    const int b = bt >> 12;                  // T_ = 4096
    float a[8] = {0.f, 0.f, 0.f, 0.f, 0.f, 0.f, 0.f, 0.f};
    for (int s = 0; s < n; ++s) {
        const u16* yrow = Ybuf + ((size_t)b * (E_ * C_) + sl[s]) * D_ + tid * 8;
        short8 v = *reinterpret_cast<const short8*>(yrow);
        #pragma unroll
        for (int j = 0; j < 8; ++j) a[j] += bf2f((u16)v[j]);
    }
    float* orow = out + (size_t)bt * D_ + tid * 8;
    *reinterpret_cast<f32x4*>(orow)     = (f32x4){a[0], a[1], a[2], a[3]};
    *reinterpret_cast<f32x4*>(orow + 4) = (f32x4){a[4], a[5], a[6], a[7]};
}

extern "C" void kernel_launch(void* const* d_in, const int* in_sizes, int n_in,
                              void* d_out, int out_size, void* d_ws, size_t ws_size,
                              hipStream_t stream) {
    const float* x    = (const float*)d_in[0];
    const float* W1   = (const float*)d_in[1];
    const float* b1   = (const float*)d_in[2];
    const float* W2   = (const float*)d_in[3];
    const float* b2   = (const float*)d_in[4];
    const int*   idx  = (const int*)d_in[5];
    const float* gate = (const float*)d_in[6];
    float* out = (float*)d_out;

    const size_t nW = (size_t)E_ * H_ * D_;        // 4,194,304
    const size_t nH = (size_t)B_ * E_ * C_ * H_;   // 8,388,608
    const size_t nY = (size_t)B_ * E_ * C_ * D_;   // 67,108,864

    // ws layout: [W1bf (plain rows)][W2img][Himg][Ybuf][cnt][slots]
    u16* W1bf  = (u16*)d_ws;
    u16* W2img = W1bf + nW;
    u16* Himg  = W2img + nW;
    u16* Ybuf  = Himg + nH;
    int* cnt   = (int*)(Ybuf + nY);
    int* slots = cnt + (size_t)B_ * T_;

    zero_cnt<<<(B_ * T_) / 1024, 256, 0, stream>>>(cnt);
    conv_f32_bf16<<<(int)(nW / 1024), 256, 0, stream>>>(W1, W1bf, (int)nW);
    conv_w2_img<<<2048, 256, 0, stream>>>(W2, W2img);
    fill_kernel<<<(B_ * E_ * C_) / 256, 256, 0, stream>>>(idx, cnt, slots);

    gemm1_v13<<<dim3(32, 8), 512, 0, stream>>>(x, W1bf, b1, idx, Himg);
    gemm2_v8<<<dim3(32, 8), 512, 0, stream>>>(Himg, W2img, b2, gate, Ybuf);
    combine_kernel<<<B_ * T_, 256, 0, stream>>>(Ybuf, cnt, slots, out);
}

// Round 19
// 202.824 us; speedup vs baseline: 1.0953x; 1.0953x over previous
//
#include <hip/hip_runtime.h>
#include <hip/hip_bf16.h>
#include <math.h>

#define B_ 4
#define T_ 4096
#define D_ 2048
#define E_ 8
#define C_ 1024
#define H_ 256
#define SLOTCAP 32

typedef unsigned short u16;
typedef unsigned long long u64;
typedef __attribute__((ext_vector_type(8))) short short8;
typedef __attribute__((ext_vector_type(4))) float f32x4;

__device__ __forceinline__ u16 f2bf_n(float f) {
    union { __hip_bfloat16 b; u16 u; } v;
    v.b = __float2bfloat16(f);
    return v.u;
}
__device__ __forceinline__ float bf2f(u16 u) {
    union { unsigned u; float f; } v; v.u = ((unsigned)u) << 16;
    return v.f;
}

// swizzled u16 index into a [rows][64] tile: 8-u16 chunk XOR'd by row&7
__device__ __forceinline__ int swz(int row, int chunk) {
    return (row << 6) + ((chunk ^ (row & 7)) << 3);
}

// async global->LDS, 16B per lane; dst wave-uniform base (HW adds lane*16)
__device__ __forceinline__ void gload16(const void* g, void* l) {
    __builtin_amdgcn_global_load_lds(
        (const __attribute__((address_space(1))) void*)g,
        (__attribute__((address_space(3))) void*)l, 16, 0, 0);
}

// ---------------- plain f32 -> bf16 (row-major W1) ----------------
__global__ __launch_bounds__(256) void conv_f32_bf16(
    const float* __restrict__ src, u16* __restrict__ dst, int n)
{
    int i = (blockIdx.x * 256 + threadIdx.x) * 4;
    if (i >= n) return;
    f32x4 v = *reinterpret_cast<const f32x4*>(src + i);
    u16 o[4];
    o[0] = f2bf_n(v[0]); o[1] = f2bf_n(v[1]); o[2] = f2bf_n(v[2]); o[3] = f2bf_n(v[3]);
    *reinterpret_cast<u64*>(dst + i) = *reinterpret_cast<const u64*>(o);
}

// ---------------- W2 -> swizzled tile image ----------------
// image[e][nt(8)][kt(4)][row(256)][sc(8)]
__global__ __launch_bounds__(256) void conv_w2_img(
    const float* __restrict__ W2, u16* __restrict__ img)
{
    const int cid = blockIdx.x * 256 + threadIdx.x;
    const int e = cid >> 16;
    const int nt = (cid >> 13) & 7;
    const int kt = (cid >> 11) & 3;
    const int row = (cid >> 3) & 255;
    const int sc = cid & 7;
    const float* s = W2 + (((size_t)e * 2048 + nt * 256 + row) * 256 + kt * 64
                           + ((sc ^ (row & 7)) << 3));
    f32x4 v0 = *reinterpret_cast<const f32x4*>(s);
    f32x4 v1 = *reinterpret_cast<const f32x4*>(s + 4);
    u16 o[8];
    #pragma unroll
    for (int j = 0; j < 4; ++j) { o[j] = f2bf_n(v0[j]); o[j + 4] = f2bf_n(v1[j]); }
    *reinterpret_cast<short8*>(img + (size_t)cid * 8) =
        *reinterpret_cast<const short8*>(o);
}

// ---------------- zero cnt ----------------
__global__ __launch_bounds__(256) void zero_cnt(int* __restrict__ cnt)
{
    const int i = (blockIdx.x * 256 + threadIdx.x) * 4;
    *reinterpret_cast<f32x4*>(cnt + i) = (f32x4){0.f, 0.f, 0.f, 0.f};
}

// ---------------- GEMM1 v12: 128x256 reg-staged dbuf (measured best) --------
// f32-A gather + in-loop cvt, B reg-staged from plain W1bf rows; dbuf LDS,
// 1 raw barrier per K-step (global loads never drained mid-loop); setprio.
// grid (x=32 be -> XCD=e, y=8 mt2); 512 thr (8 waves 2Mx4N); 1 block/CU.
// Epilogue writes Himg 64-row tile images (gemm2_v8's A layout).
__global__ __launch_bounds__(512) void gemm1_v12(
    const float* __restrict__ x, const u16* __restrict__ W1bf,
    const float* __restrict__ b1, const int* __restrict__ idx,
    u16* __restrict__ Himg)
{
    const int be = blockIdx.x;          // XCD = be%8 = e
    const int mt2 = blockIdx.y;         // 0..7
    const int b = be >> 3, e = be & 7;
    const int m0 = mt2 * 128;

    __shared__ __align__(16) u16 As[2][128 * 64];
    __shared__ __align__(16) u16 Bs[2][256 * 64];
    __shared__ int toks[128];
    __shared__ float bs1[256];

    const int tid = threadIdx.x;
    if (tid < 128) toks[tid] = idx[(b * E_ + e) * C_ + m0 + tid];
    if (tid < 256) bs1[tid] = b1[e * H_ + tid];
    __syncthreads();

    const int lane = tid & 63, wid = tid >> 6;
    const int wm = wid >> 2, wn = wid & 3;
    const int l15 = lane & 15, lk = lane >> 4;

    // A staging: row ar (0..127), chunks ac0 / ac0+4 (f32 source, cvt here)
    const int ar = tid >> 2, ac0 = tid & 3;
    const float* aRow = x + (size_t)b * (T_ * (size_t)D_)
                          + (size_t)toks[ar] * D_;
    // B staging: row br (0..255), chunks bc0..bc0+3 (bf16 source)
    const int br = tid >> 1, bc0 = (tid & 1) * 4;
    const u16* bRow = W1bf + ((size_t)e * H_ + br) * D_;

    const int aOff0 = swz(ar, ac0), aOff1 = swz(ar, ac0 + 4);
    int bOff[4];
    #pragma unroll
    for (int j = 0; j < 4; ++j) bOff[j] = swz(br, bc0 + j);

    f32x4 acc[4][4];
    #pragma unroll
    for (int i = 0; i < 4; ++i)
        #pragma unroll
        for (int j = 0; j < 4; ++j)
            acc[i][j] = (f32x4){0.f, 0.f, 0.f, 0.f};

    f32x4 pa[4];
    short8 pb[4];

#define G1_LOAD(k)                                                            \
    do {                                                                      \
        pa[0] = *reinterpret_cast<const f32x4*>(aRow + (k) + ac0 * 8);        \
        pa[1] = *reinterpret_cast<const f32x4*>(aRow + (k) + ac0 * 8 + 4);    \
        pa[2] = *reinterpret_cast<const f32x4*>(aRow + (k) + (ac0 + 4) * 8);  \
        pa[3] = *reinterpret_cast<const f32x4*>(aRow + (k) + (ac0 + 4) * 8 + 4);\
        _Pragma("unroll")                                                     \
        for (int j = 0; j < 4; ++j)                                           \
            pb[j] = *reinterpret_cast<const short8*>(bRow + (k) + (bc0 + j) * 8);\
    } while (0)

#define G1_WRITE(buf)                                                         \
    do {                                                                      \
        short8 s0, s1;                                                        \
        _Pragma("unroll")                                                     \
        for (int r = 0; r < 4; ++r) {                                         \
            s0[r] = (short)f2bf_n(pa[0][r]); s0[r + 4] = (short)f2bf_n(pa[1][r]); \
            s1[r] = (short)f2bf_n(pa[2][r]); s1[r + 4] = (short)f2bf_n(pa[3][r]); \
        }                                                                     \
        *reinterpret_cast<short8*>(&As[buf][aOff0]) = s0;                     \
        *reinterpret_cast<short8*>(&As[buf][aOff1]) = s1;                     \
        _Pragma("unroll")                                                     \
        for (int j = 0; j < 4; ++j)                                           \
            *reinterpret_cast<short8*>(&Bs[buf][bOff[j]]) = pb[j];            \
    } while (0)

    // prologue: tile 0 into buf0; tile 1 into regs
    G1_LOAD(0);
    G1_WRITE(0);
    G1_LOAD(64);
    asm volatile("s_waitcnt lgkmcnt(0)" ::: "memory");
    __builtin_amdgcn_s_barrier();

    const int NT = D_ / 64;  // 32
    for (int t = 0; t < NT; ++t) {
        const int cur = t & 1;
        if (t + 1 < NT) G1_WRITE(cur ^ 1);     // t+1 regs -> alt buf, overlaps MFMA
        if (t + 2 < NT) G1_LOAD((t + 2) * 64); // stays in flight across barrier
        #pragma unroll
        for (int kk = 0; kk < 2; ++kk) {
            short8 af[4], bfr[4];
            #pragma unroll
            for (int m = 0; m < 4; ++m) {
                const int row = wm * 64 + m * 16 + l15;
                af[m] = *reinterpret_cast<const short8*>(
                    &As[cur][swz(row, kk * 4 + lk)]);
            }
            #pragma unroll
            for (int n = 0; n < 4; ++n) {
                const int row = wn * 64 + n * 16 + l15;
                bfr[n] = *reinterpret_cast<const short8*>(
                    &Bs[cur][swz(row, kk * 4 + lk)]);
            }
            __builtin_amdgcn_s_setprio(1);
            #pragma unroll
            for (int m = 0; m < 4; ++m)
                #pragma unroll
                for (int n = 0; n < 4; ++n)
                    acc[m][n] = __builtin_amdgcn_mfma_f32_16x16x32_bf16(
                        bfr[n], af[m], acc[m][n], 0, 0, 0);
            __builtin_amdgcn_s_setprio(0);
        }
        // own ds ops drained; global loads deliberately NOT drained
        asm volatile("s_waitcnt lgkmcnt(0)" ::: "memory");
        __builtin_amdgcn_s_barrier();
    }
#undef G1_LOAD
#undef G1_WRITE

    // epilogue: bias + exact gelu -> Himg (64-row tile images, gemm2 A layout)
    // cl in [0,128): image = mt2*2 + (cl>>6), row = cl&63; kt = wn;
    // lc = (2n + (lk>>1)) ^ (row&7); half-chunk offset = (lk&1)*4.
    #pragma unroll
    for (int m = 0; m < 4; ++m) {
        const int cl = wm * 64 + m * 16 + l15;
        const int row = cl & 63;
        const size_t hblk =
            ((size_t)(be * 16 + mt2 * 2 + (cl >> 6)) * 4 + wn) * 4096;
        #pragma unroll
        for (int n = 0; n < 4; ++n) {
            const int hb = wn * 64 + n * 16 + lk * 4;
            u16 o[4];
            #pragma unroll
            for (int r = 0; r < 4; ++r) {
                float h = acc[m][n][r] + bs1[hb + r];
                float g = 0.5f * h * (1.0f + erff(h * 0.70710678118f));
                o[r] = f2bf_n(g);
            }
            const int lc = (n * 2 + (lk >> 1)) ^ (row & 7);
            u16* p = Himg + hblk + row * 64 + lc * 8 + (lk & 1) * 4;
            *reinterpret_cast<u64*>(p) = *reinterpret_cast<const u64*>(o);
        }
    }
}

// ---------------- GEMM2 v8: persistent B-panel; no store drain in loop -----
__global__ __launch_bounds__(512) void gemm2_v8(
    const u16* __restrict__ Himg, const u16* __restrict__ W2img,
    const float* __restrict__ b2, const float* __restrict__ gate,
    u16* __restrict__ Ybuf)
{
    const int be = blockIdx.x;          // XCD = be%8 = e
    const int nt = blockIdx.y;          // 0..7
    const int b = be >> 3, e = be & 7;
    const int n0 = nt * 256;

    __shared__ __align__(16) u16 As[16384];   // 32 KB: [kt4][row64][sc8]
    __shared__ __align__(16) u16 Bs[65536];   // 128 KB: [kt4][row256][sc8]

    const int tid = threadIdx.x;
    const int lane = tid & 63, wid = tid >> 6;
    const int wm = wid >> 2, wn = wid & 3;
    const int l15 = lane & 15, lk = lane >> 4;
    const int wofs = wid * 512;

    const u16* bPanel = W2img + (size_t)(e * 8 + nt) * 65536;
    #pragma unroll
    for (int j = 0; j < 16; ++j)
        gload16(bPanel + (size_t)(j * 512 + tid) * 8, &Bs[j * 4096 + wofs]);

    const u16* aBase = Himg + (size_t)(be * 16) * 16384 + (size_t)tid * 8;

#define A_ISSUE(mt)                                                           \
    do {                                                                      \
        const u16* a_ = aBase + (size_t)(mt) * 16384;                         \
        gload16(a_,          &As[wofs]);                                      \
        gload16(a_ + 4096,   &As[4096 + wofs]);                               \
        gload16(a_ + 8192,   &As[8192 + wofs]);                               \
        gload16(a_ + 12288,  &As[12288 + wofs]);                              \
    } while (0)

    A_ISSUE(0);

    f32x4 bias[4];
    #pragma unroll
    for (int n = 0; n < 4; ++n)
        bias[n] = *reinterpret_cast<const f32x4*>(
            &b2[n0 + wn * 64 + n * 16 + lk * 4]);

    const int gbase = (b * E_ + e) * C_ + wm * 32 + l15;
    const size_t ybase = (size_t)(b * E_ + e) * C_;

    float gc0 = gate[gbase];
    float gc1 = gate[gbase + 16];

    asm volatile("s_waitcnt vmcnt(0)" ::: "memory");   // B panel + A(0) + gate
    __builtin_amdgcn_s_barrier();
    __builtin_amdgcn_sched_barrier(0);

    for (int mt = 0; mt < 16; ++mt) {
        f32x4 acc[2][4];
        #pragma unroll
        for (int i = 0; i < 2; ++i)
            #pragma unroll
            for (int j = 0; j < 4; ++j)
                acc[i][j] = (f32x4){0.f, 0.f, 0.f, 0.f};

        #pragma unroll
        for (int t = 0; t < 4; ++t) {
            #pragma unroll
            for (int kk = 0; kk < 2; ++kk) {
                short8 af[2], bfr[4];
                #pragma unroll
                for (int m = 0; m < 2; ++m) {
                    const int row = wm * 32 + m * 16 + l15;
                    af[m] = *reinterpret_cast<const short8*>(
                        &As[t * 4096 + swz(row, kk * 4 + lk)]);
                }
                #pragma unroll
                for (int n = 0; n < 4; ++n) {
                    const int row = wn * 64 + n * 16 + l15;
                    bfr[n] = *reinterpret_cast<const short8*>(
                        &Bs[t * 16384 + swz(row, kk * 4 + lk)]);
                }
                __builtin_amdgcn_s_setprio(1);
                #pragma unroll
                for (int m = 0; m < 2; ++m)
                    #pragma unroll
                    for (int n = 0; n < 4; ++n)
                        acc[m][n] = __builtin_amdgcn_mfma_f32_16x16x32_bf16(
                            bfr[n], af[m], acc[m][n], 0, 0, 0);
                __builtin_amdgcn_s_setprio(0);
            }
        }

        asm volatile("s_waitcnt lgkmcnt(0)" ::: "memory");
        __builtin_amdgcn_s_barrier();
        __builtin_amdgcn_sched_barrier(0);

        if (mt < 15) A_ISSUE(mt + 1);
        float gn0 = 0.f, gn1 = 0.f;
        if (mt < 15) {
            gn0 = gate[gbase + (mt + 1) * 64];
            gn1 = gate[gbase + (mt + 1) * 64 + 16];
        }

        #pragma unroll
        for (int m = 0; m < 2; ++m) {
            const int cl = wm * 32 + m * 16 + l15;
            const float g = (m == 0) ? gc0 : gc1;
            u16* rowp = Ybuf + (ybase + mt * 64 + cl) * (size_t)D_ + n0;
            #pragma unroll
            for (int n = 0; n < 4; ++n) {
                const int db = wn * 64 + n * 16 + lk * 4;
                u16 o[4];
                #pragma unroll
                for (int r = 0; r < 4; ++r)
                    o[r] = f2bf_n((acc[m][n][r] + bias[n][r]) * g);
                *reinterpret_cast<u64*>(rowp + db) =
                    *reinterpret_cast<const u64*>(o);
            }
        }

        if (mt < 15) {
            // newest 18 = 16 stores + 2 gate loads -> A(mt+1) retired,
            // stores free-run
            asm volatile("s_waitcnt vmcnt(18)" ::: "memory");
            __builtin_amdgcn_s_barrier();
            __builtin_amdgcn_sched_barrier(0);
        }
        gc0 = gn0; gc1 = gn1;
    }
#undef A_ISSUE
}

// ---------------- inverted index build ----------------
__global__ __launch_bounds__(256) void fill_kernel(
    const int* __restrict__ idx, int* __restrict__ cnt,
    int* __restrict__ slots)
{
    int i = blockIdx.x * 256 + threadIdx.x;
    if (i >= B_ * E_ * C_) return;
    int b = i / (E_ * C_);
    int slot = i % (E_ * C_);
    int t = idx[i];
    int p = atomicAdd(&cnt[b * T_ + t], 1);
    if (p < SLOTCAP) slots[(b * T_ + t) * SLOTCAP + p] = slot;
}

// ---------------- combine: out[b,t,:] = sum over slots of Ybuf ----------------
__global__ __launch_bounds__(256) void combine_kernel(
    const u16* __restrict__ Ybuf, const int* __restrict__ cnt,
    const int* __restrict__ slots, float* __restrict__ out)
{
    const int bt = blockIdx.x;               // b*T_ + t
    const int tid = threadIdx.x;
    __shared__ int sl[SLOTCAP];
    int n = cnt[bt];
    n = n > SLOTCAP ? SLOTCAP : n;
    if (tid < n) sl[tid] = slots[bt * SLOTCAP + tid];
    __syncthreads();
    const int b = bt >> 12;                  // T_ = 4096
    float a[8] = {0.f, 0.f, 0.f, 0.f, 0.f, 0.f, 0.f, 0.f};
    for (int s = 0; s < n; ++s) {
        const u16* yrow = Ybuf + ((size_t)b * (E_ * C_) + sl[s]) * D_ + tid * 8;
        short8 v = *reinterpret_cast<const short8*>(yrow);
        #pragma unroll
        for (int j = 0; j < 8; ++j) a[j] += bf2f((u16)v[j]);
    }
    float* orow = out + (size_t)bt * D_ + tid * 8;
    *reinterpret_cast<f32x4*>(orow)     = (f32x4){a[0], a[1], a[2], a[3]};
    *reinterpret_cast<f32x4*>(orow + 4) = (f32x4){a[4], a[5], a[6], a[7]};
}

extern "C" void kernel_launch(void* const* d_in, const int* in_sizes, int n_in,
                              void* d_out, int out_size, void* d_ws, size_t ws_size,
                              hipStream_t stream) {
    const float* x    = (const float*)d_in[0];
    const float* W1   = (const float*)d_in[1];
    const float* b1   = (const float*)d_in[2];
    const float* W2   = (const float*)d_in[3];
    const float* b2   = (const float*)d_in[4];
    const int*   idx  = (const int*)d_in[5];
    const float* gate = (const float*)d_in[6];
    float* out = (float*)d_out;

    const size_t nW = (size_t)E_ * H_ * D_;        // 4,194,304
    const size_t nH = (size_t)B_ * E_ * C_ * H_;   // 8,388,608
    const size_t nY = (size_t)B_ * E_ * C_ * D_;   // 67,108,864

    // ws layout: [W1bf (plain rows)][W2img][Himg][Ybuf][cnt][slots]
    u16* W1bf  = (u16*)d_ws;
    u16* W2img = W1bf + nW;
    u16* Himg  = W2img + nW;
    u16* Ybuf  = Himg + nH;
    int* cnt   = (int*)(Ybuf + nY);
    int* slots = cnt + (size_t)B_ * T_;

    zero_cnt<<<(B_ * T_) / 1024, 256, 0, stream>>>(cnt);
    conv_f32_bf16<<<(int)(nW / 1024), 256, 0, stream>>>(W1, W1bf, (int)nW);
    conv_w2_img<<<2048, 256, 0, stream>>>(W2, W2img);
    fill_kernel<<<(B_ * E_ * C_) / 256, 256, 0, stream>>>(idx, cnt, slots);

    gemm1_v12<<<dim3(32, 8), 512, 0, stream>>>(x, W1bf, b1, idx, Himg);
    gemm2_v8<<<dim3(32, 8), 512, 0, stream>>>(Himg, W2img, b2, gate, Ybuf);
    combine_kernel<<<B_ * T_, 256, 0, stream>>>(Ybuf, cnt, slots, out);
}